// Round 11
// baseline (177.274 us; speedup 1.0000x reference)
//
#include <hip/hip_runtime.h>

#define IN_SIZE 11
#define HID 16
#define FEAT 18
#define TSTEPS 18
#define NBLOCKS 1024
#define CNT_OFF_BYTES 32768   // byte offset of barrier counter in d_ws

__device__ __forceinline__ float fast_rcp(float v) { return __builtin_amdgcn_rcpf(v); }

// broadcast a float from a fixed lane via v_readlane (SGPR path, no DS)
__device__ __forceinline__ float rl(float v, int lane) {
    return __int_as_float(__builtin_amdgcn_readlane(__float_as_int(v), lane));
}

// Single launch, two phases, manual device-scope barrier.
//   Phase 1: coalesced rise-scan of sorted batch[] -> first_arr[0..B].
//            Thread tid owns 32 elements (8x int4). Rise batch[j]>batch[j-1]
//            writes first_arr[v]=j for v in (batch[j-1], batch[j]] via
//            atomicExch (device-scope -> coherence point).
//   Barrier: per-block atomicAdd arrival on counter (zeroed by a 4-byte
//            hipMemsetAsync each call); thread-0 spins on an agent-scope
//            (sc1, L2-bypassing) load; capacity co-residency: 1024 blocks
//            at 4 blocks/CU x 256 CUs -> no deadlock.
//   Phase 2: one WAVE per graph (r8-validated body): boundaries (agent
//            loads) -> edge fetch -> x gather -> readlane LSTM -> fc.
__global__ __launch_bounds__(256, 4)
void tgnn_lstm_onekernel(const float* __restrict__ x,
                         const float* __restrict__ W_ih,
                         const float* __restrict__ W_hh,
                         const float* __restrict__ b_ih,
                         const float* __restrict__ b_hh,
                         const float* __restrict__ W_fc,
                         const float* __restrict__ b_fc,
                         const int* __restrict__ edge_index,
                         const int* __restrict__ edge_attr,
                         const int* __restrict__ batch,
                         int* __restrict__ first_arr,
                         int* __restrict__ barrier_cnt,
                         float* __restrict__ out,
                         int E, int B)
{
    const int tid = blockIdx.x * blockDim.x + threadIdx.x;
    const int wl  = threadIdx.x & 63;
    const int g   = tid >> 6;            // wave id = graph
    const int u   = wl & 15;
    const int r   = wl >> 4;
    const int row = wl;

    // ---------------- Phase 1: coalesced rise-scan (32 elems/thread) --------
    {
        const long long base = (long long)tid * 32;
        if (base < E) {
            if (base + 32 <= E) {
                const int prev = (base == 0) ? -1 : batch[base - 1];
                const int4* bp = reinterpret_cast<const int4*>(batch + base);
                const int4 q0 = bp[0], q1 = bp[1], q2 = bp[2], q3 = bp[3];
                const int4 q4 = bp[4], q5 = bp[5], q6 = bp[6], q7 = bp[7];
                if (q7.w > prev) {                   // rare: rise in this chunk
                    const int v[33] = {prev,
                        q0.x,q0.y,q0.z,q0.w, q1.x,q1.y,q1.z,q1.w,
                        q2.x,q2.y,q2.z,q2.w, q3.x,q3.y,q3.z,q3.w,
                        q4.x,q4.y,q4.z,q4.w, q5.x,q5.y,q5.z,q5.w,
                        q6.x,q6.y,q6.z,q6.w, q7.x,q7.y,q7.z,q7.w};
#pragma unroll
                    for (int s = 1; s <= 32; ++s) {
                        if (v[s] > v[s - 1]) {
                            const int j = (int)base + s - 1;
                            for (int g2 = v[s - 1] + 1; g2 <= v[s]; ++g2)
                                atomicExch(&first_arr[g2], j);
                        }
                    }
                }
                if (base + 32 >= E) {                // tail above batch[E-1]
                    for (int g2 = q7.w + 1; g2 <= B; ++g2)
                        atomicExch(&first_arr[g2], E);
                }
            } else {                                 // partial last chunk
                int pv = (base == 0) ? -1 : batch[base - 1];
                for (long long j = base; j < E; ++j) {
                    const int bv = batch[j];
                    if (bv > pv)
                        for (int g2 = pv + 1; g2 <= bv; ++g2)
                            atomicExch(&first_arr[g2], (int)j);
                    pv = bv;
                }
                const int bl = batch[E - 1];
                for (int g2 = bl + 1; g2 <= B; ++g2)
                    atomicExch(&first_arr[g2], E);
            }
        }
    }

    // ---------------- Barrier (device scope, coherence-point traffic) -------
    __threadfence();
    __syncthreads();
    if (threadIdx.x == 0) {
        atomicAdd(barrier_cnt, 1);
        while (__hip_atomic_load(barrier_cnt, __ATOMIC_ACQUIRE,
                                 __HIP_MEMORY_SCOPE_AGENT) < NBLOCKS)
            __builtin_amdgcn_s_sleep(8);
    }
    __syncthreads();

    if (g >= B) return;

    // ---------------- Phase 2: boundaries (agent loads bypass stale L2) -----
    const int f0 = __hip_atomic_load(&first_arr[g],     __ATOMIC_RELAXED,
                                     __HIP_MEMORY_SCOPE_AGENT);
    const int f1 = __hip_atomic_load(&first_arr[g + 1], __ATOMIC_RELAXED,
                                     __HIP_MEMORY_SCOPE_AGENT);
    int cnt = f1 - f0;
    cnt = (cnt < 0) ? 0 : ((cnt > TSTEPS) ? TSTEPS : cnt);

    // ---- edge fetch: lane t (t<18) loads step t's ids + attr (one round) ----
    int n1 = 0, n2 = 0, ea = 0;
    if (wl < TSTEPS) {
        int j = f0 + wl;
        if (j > E - 1) j = E - 1;
        n1 = edge_index[j];
        n2 = edge_index[E + j];
        ea = edge_attr[j];               // in [0,7) even when clamped
    }

    // ---- per-lane weights (independent; overlap edge/x latency) ----
    float wih[IN_SIZE], whh[HID];
#pragma unroll
    for (int k = 0; k < IN_SIZE; ++k) wih[k] = W_ih[row * FEAT + k];
#pragma unroll
    for (int v = 0; v < HID; ++v) whh[v] = W_hh[row * HID + v];
    const float bias = b_ih[row] + b_hh[row];
    const float wfc  = W_fc[row];
    const float bfc  = b_fc[r];

    // ---- x gather: lane t holds step t's 11 summed features (one round) ----
    float f[IN_SIZE];
    {
        const float* xa = x + (long)n1 * IN_SIZE;
        const float* xb = x + (long)n2 * IN_SIZE;
#pragma unroll
        for (int k = 0; k < IN_SIZE; ++k) f[k] = xa[k] + xb[k];
    }
    if (wl >= cnt) {                     // invalid steps AND lanes >= 18
#pragma unroll
        for (int k = 0; k < IN_SIZE; ++k) f[k] = 0.0f;
    }

    // ---- prologue: a_in[t] = bias + x_t . wih_row + onehot-weight ----
    float ain[TSTEPS];
#pragma unroll
    for (int t = 0; t < TSTEPS; ++t) {
        const int eat = __builtin_amdgcn_readlane(ea, t);   // uniform
        const float w1 = W_ih[row * FEAT + IN_SIZE + eat];  // L1-hot (4.6 KB)
        float a = bias + ((t < cnt) ? w1 : 0.0f);
#pragma unroll
        for (int k = 0; k < IN_SIZE; ++k)
            a = fmaf(rl(f[k], t), wih[k], a);
        ain[t] = a;
    }

    // ---- LSTM: per step 16 readlane + 16 FMA + 1 own-gate act + 3 swizzles ----
    const float sa = (r == 2) ? -2.0f : -1.0f;   // r==2 -> tanh via 2*sig(2a)-1
    const float ma = (r == 2) ?  2.0f :  1.0f;
    const float oa = (r == 2) ? -1.0f :  0.0f;

    float h = 0.0f, c = 0.0f;
#pragma unroll
    for (int t = 0; t < TSTEPS; ++t) {
        float a;
        if (t == 0) {
            a = ain[0];
        } else {
            float A0 = ain[t], A1 = 0.0f, A2 = 0.0f, A3 = 0.0f;
#pragma unroll
            for (int v = 0; v < HID; v += 4) {
                A0 = fmaf(rl(h, v + 0), whh[v + 0], A0);
                A1 = fmaf(rl(h, v + 1), whh[v + 1], A1);
                A2 = fmaf(rl(h, v + 2), whh[v + 2], A2);
                A3 = fmaf(rl(h, v + 3), whh[v + 3], A3);
            }
            a = (A0 + A1) + (A2 + A3);
        }
        const float act = fmaf(ma, fast_rcp(1.0f + __expf(sa * a)), oa);
        const float s1 = __shfl_xor(act, 16, 64);   // sigma(f)
        const float s2 = __shfl_xor(act, 32, 64);   // tanh(g)
        const float s3 = __shfl_xor(s1, 32, 64);    // sigma(o)
        c = fmaf(s1, c, act * s2);                  // lanes 0..15 valid
        const float th = fmaf(2.0f, fast_rcp(1.0f + __expf(-2.0f * c)), -1.0f);
        h = s3 * th;
    }

    // ---- fc epilogue ----
    const float hb = __shfl(h, u, 64);              // lane wl <- h[u] from lane u
    float p = hb * wfc;                             // W_fc[r][u] == W_fc[row]
#pragma unroll
    for (int m = 8; m >= 1; m >>= 1) p += __shfl_xor(p, m, 16);
    if (u == 0) out[g * 4 + r] = p + bfc;
}

extern "C" void kernel_launch(void* const* d_in, const int* in_sizes, int n_in,
                              void* d_out, int out_size, void* d_ws, size_t ws_size,
                              hipStream_t stream) {
    const float* x     = (const float*)d_in[0];
    const float* W_ih  = (const float*)d_in[1];
    const float* W_hh  = (const float*)d_in[2];
    const float* b_ih  = (const float*)d_in[3];
    const float* b_hh  = (const float*)d_in[4];
    const float* W_fc  = (const float*)d_in[5];
    const float* b_fc  = (const float*)d_in[6];
    const int* edge_index = (const int*)d_in[7];
    const int* edge_attr  = (const int*)d_in[8];
    const int* batch      = (const int*)d_in[9];

    const int E = in_sizes[8];            // N_EDGES
    const int B = out_size / 4;           // N_GRAPHS

    int* first_arr   = (int*)d_ws;                            // (B+1) ints
    int* barrier_cnt = (int*)((char*)d_ws + CNT_OFF_BYTES);   // 1 int

    hipMemsetAsync(barrier_cnt, 0, 4, stream);                // zero each call

    tgnn_lstm_onekernel<<<NBLOCKS, 256, 0, stream>>>(
        x, W_ih, W_hh, b_ih, b_hh, W_fc, b_fc,
        edge_index, edge_attr, batch,
        first_arr, barrier_cnt, (float*)d_out, E, B);
}

// Round 12
// 29.690 us; speedup vs baseline: 5.9708x; 5.9708x over previous
//
#include <hip/hip_runtime.h>

#define IN_SIZE 11
#define HID 16
#define FEAT 18
#define TSTEPS 18
#define CAP 1024   // LDS entry list capacity; this input yields ~4-15 per block

__device__ __forceinline__ float fast_rcp(float v) { return __builtin_amdgcn_rcpf(v); }

// broadcast a float from a fixed lane via v_readlane (SGPR path, no DS)
__device__ __forceinline__ float rl(float v, int lane) {
    return __int_as_float(__builtin_amdgcn_readlane(__float_as_int(v), lane));
}

// Single kernel, block-local two phases (no grid sync anywhere):
//   Phase 1 (detect): block scans slice [base0, base0+8192) of sorted batch[]
//     coalesced (32 ints/thread via 8x int4). A rise batch[j] > batch[j-1]
//     identifies first[v] = j; push (v, j) to an LDS list. Value gaps and the
//     tail above batch[E-1] push (v, -1) = empty graph (cnt 0). Each graph is
//     discovered by exactly one thread grid-wide.
//   Phase 2 (process): the block's 4 waves loop over the LDS list; each wave
//     runs the r8-validated body for its graph: cnt = run-length of g at j
//     (ballot over batch[j..j+17], contiguous), edge fetch, x gather,
//     readlane LSTM, fc epilogue.
extern "C" __global__ __launch_bounds__(256, 4)
void tgnn_rise_lstm(const float* __restrict__ x,
                    const float* __restrict__ W_ih,
                    const float* __restrict__ W_hh,
                    const float* __restrict__ b_ih,
                    const float* __restrict__ b_hh,
                    const float* __restrict__ W_fc,
                    const float* __restrict__ b_fc,
                    const int* __restrict__ edge_index,
                    const int* __restrict__ edge_attr,
                    const int* __restrict__ batch,
                    float* __restrict__ out,
                    int E, int B)
{
    __shared__ int lcnt;
    __shared__ int lg[CAP];
    __shared__ int lj[CAP];

    if (threadIdx.x == 0) lcnt = 0;
    __syncthreads();

    auto push = [&](int g2, int j) {
        const int slot = atomicAdd(&lcnt, 1);
        if (slot < CAP) { lg[slot] = g2; lj[slot] = j; }
    };

    // ---------------- Phase 1: coalesced rise detection (32 ints/thread) ----
    {
        const long long base = ((long long)blockIdx.x * blockDim.x + threadIdx.x) * 32;
        if (base < E) {
            if (base + 32 <= E) {
                const int prev = (base == 0) ? -1 : batch[base - 1];
                const int4* bp = reinterpret_cast<const int4*>(batch + base);
                const int4 q0 = bp[0], q1 = bp[1], q2 = bp[2], q3 = bp[3];
                const int4 q4 = bp[4], q5 = bp[5], q6 = bp[6], q7 = bp[7];
                if (q7.w > prev) {                     // rare: rise in chunk
                    const int v[33] = {prev,
                        q0.x,q0.y,q0.z,q0.w, q1.x,q1.y,q1.z,q1.w,
                        q2.x,q2.y,q2.z,q2.w, q3.x,q3.y,q3.z,q3.w,
                        q4.x,q4.y,q4.z,q4.w, q5.x,q5.y,q5.z,q5.w,
                        q6.x,q6.y,q6.z,q6.w, q7.x,q7.y,q7.z,q7.w};
#pragma unroll
                    for (int s = 1; s <= 32; ++s) {
                        if (v[s] > v[s - 1]) {
                            const int j = (int)base + s - 1;
                            for (int g2 = v[s - 1] + 1; g2 <= v[s]; ++g2)
                                push(g2, (g2 == v[s]) ? j : -1);
                        }
                    }
                }
                if (base + 32 == E) {                  // tail: graphs > batch[E-1]
                    for (int g2 = q7.w + 1; g2 < B; ++g2) push(g2, -1);
                }
            } else {                                   // partial last chunk
                int pv = (base == 0) ? -1 : batch[base - 1];
                for (long long jj = base; jj < E; ++jj) {
                    const int bv = batch[jj];
                    if (bv > pv)
                        for (int g2 = pv + 1; g2 <= bv; ++g2)
                            push(g2, (g2 == bv) ? (int)jj : -1);
                    pv = bv;
                }
                for (int g2 = pv + 1; g2 < B; ++g2) push(g2, -1);
            }
        }
    }
    __syncthreads();                                   // block-local only
    const int n = (lcnt < CAP) ? lcnt : CAP;

    // ---------------- Phase 2: per-wave LSTM over discovered graphs ---------
    const int wl  = threadIdx.x & 63;
    const int wid = threadIdx.x >> 6;
    const int u   = wl & 15;
    const int r   = wl >> 4;
    const int row = wl;

    // per-lane weights (loaded once; L2-hot after the first blocks)
    float wih[IN_SIZE], whh[HID];
#pragma unroll
    for (int k = 0; k < IN_SIZE; ++k) wih[k] = W_ih[row * FEAT + k];
#pragma unroll
    for (int v = 0; v < HID; ++v) whh[v] = W_hh[row * HID + v];
    const float bias = b_ih[row] + b_hh[row];
    const float wfc  = W_fc[row];
    const float bfc  = b_fc[r];

    const float sa = (r == 2) ? -2.0f : -1.0f;   // own-gate act: r==2 -> tanh
    const float ma = (r == 2) ?  2.0f :  1.0f;
    const float oa = (r == 2) ? -1.0f :  0.0f;

    for (int e = wid; e < n; e += 4) {
        const int g2   = lg[e];
        const int jraw = lj[e];
        const int j    = (jraw < 0) ? 0 : jraw;

        // batch-run + edge fetch: lanes 0..17, contiguous rows (one round)
        int bj = -1, n1 = 0, n2 = 0, ea = 0;
        if (wl < TSTEPS) {
            const int idx  = j + wl;
            const int cidx = (idx > E - 1) ? E - 1 : idx;
            bj = (idx < E) ? batch[cidx] : -1;
            n1 = edge_index[cidx];
            n2 = edge_index[E + cidx];
            ea = edge_attr[cidx];            // in [0,7) even when clamped
        }
        const unsigned long long mask = __ballot(bj == g2);
        int cnt = (jraw < 0) ? 0 : (int)__builtin_ctzll(~mask);  // run length
        if (cnt > TSTEPS) cnt = TSTEPS;

        // x gather: lane t holds step t's 11 summed features (one round)
        float f[IN_SIZE];
        {
            const float* xa = x + (long)n1 * IN_SIZE;
            const float* xb = x + (long)n2 * IN_SIZE;
#pragma unroll
            for (int k = 0; k < IN_SIZE; ++k) f[k] = xa[k] + xb[k];
        }
        if (wl >= cnt) {
#pragma unroll
            for (int k = 0; k < IN_SIZE; ++k) f[k] = 0.0f;
        }

        // prologue: a_in[t] = bias + x_t . wih_row + onehot-weight
        float ain[TSTEPS];
#pragma unroll
        for (int t = 0; t < TSTEPS; ++t) {
            const int eat = __builtin_amdgcn_readlane(ea, t);   // uniform
            const float w1 = W_ih[row * FEAT + IN_SIZE + eat];  // L1-hot
            float a = bias + ((t < cnt) ? w1 : 0.0f);
#pragma unroll
            for (int k = 0; k < IN_SIZE; ++k)
                a = fmaf(rl(f[k], t), wih[k], a);
            ain[t] = a;
        }

        // LSTM: 16 readlane + 16 FMA + 1 own-gate act + 3 swizzles per step
        float h = 0.0f, c = 0.0f;
#pragma unroll
        for (int t = 0; t < TSTEPS; ++t) {
            float a;
            if (t == 0) {
                a = ain[0];
            } else {
                float A0 = ain[t], A1 = 0.0f, A2 = 0.0f, A3 = 0.0f;
#pragma unroll
                for (int v = 0; v < HID; v += 4) {
                    A0 = fmaf(rl(h, v + 0), whh[v + 0], A0);
                    A1 = fmaf(rl(h, v + 1), whh[v + 1], A1);
                    A2 = fmaf(rl(h, v + 2), whh[v + 2], A2);
                    A3 = fmaf(rl(h, v + 3), whh[v + 3], A3);
                }
                a = (A0 + A1) + (A2 + A3);
            }
            const float act = fmaf(ma, fast_rcp(1.0f + __expf(sa * a)), oa);
            const float s1 = __shfl_xor(act, 16, 64);   // sigma(f)
            const float s2 = __shfl_xor(act, 32, 64);   // tanh(g)
            const float s3 = __shfl_xor(s1, 32, 64);    // sigma(o)
            c = fmaf(s1, c, act * s2);                  // lanes 0..15 valid
            const float th = fmaf(2.0f, fast_rcp(1.0f + __expf(-2.0f * c)), -1.0f);
            h = s3 * th;
        }

        // fc epilogue
        const float hb = __shfl(h, u, 64);
        float p = hb * wfc;
#pragma unroll
        for (int m = 8; m >= 1; m >>= 1) p += __shfl_xor(p, m, 16);
        if (u == 0) out[g2 * 4 + r] = p + bfc;
    }
}

extern "C" void kernel_launch(void* const* d_in, const int* in_sizes, int n_in,
                              void* d_out, int out_size, void* d_ws, size_t ws_size,
                              hipStream_t stream) {
    const float* x     = (const float*)d_in[0];
    const float* W_ih  = (const float*)d_in[1];
    const float* W_hh  = (const float*)d_in[2];
    const float* b_ih  = (const float*)d_in[3];
    const float* b_hh  = (const float*)d_in[4];
    const float* W_fc  = (const float*)d_in[5];
    const float* b_fc  = (const float*)d_in[6];
    const int* edge_index = (const int*)d_in[7];
    const int* edge_attr  = (const int*)d_in[8];
    const int* batch      = (const int*)d_in[9];

    const int E = in_sizes[8];            // N_EDGES
    const int B = out_size / 4;           // N_GRAPHS

    const int nthr = (E + 31) / 32;       // one thread per 32 batch elements
    const int grid = (nthr + 255) / 256;  // 977 blocks for E=8M

    tgnn_rise_lstm<<<grid, 256, 0, stream>>>(x, W_ih, W_hh, b_ih, b_hh,
                                             W_fc, b_fc,
                                             edge_index, edge_attr, batch,
                                             (float*)d_out, E, B);
}